// Round 12
// baseline (4122.536 us; speedup 1.0000x reference)
//
#include <hip/hip_runtime.h>

typedef _Float16 half2_t __attribute__((ext_vector_type(2)));

#define NB 64
#define NT 2048
#define ND 256
#define NH 256
#define NTHR 256
#define NCONS 32           // 32 consumer WGs x 2 batches each
#define GRID (NCONS + 192) // + 192 producers (3 gates x 64 batches)
#define CHUNK 32
#define NCHUNK (NT / CHUNK)   // 64

// LDS (dword units). Producer: x-stage [32 t][132]. Consumer: batch0 hq bytes
// 0..255 / vq 256..511; batch1 hq 512..767 / vq 768..1023.
#define XT_STRIDE 132
#define LDS_DW (32 * XT_STRIDE + 16)

__device__ __forceinline__ float sigmoid_f(float x) { return 1.f / (1.f + __expf(-x)); }
__device__ __forceinline__ float tanh_f(float x)    { return 1.f - 2.f / (1.f + __expf(2.f * x)); }
__device__ __forceinline__ half2_t mkh2(float a, float b) {
    half2_t r; r.x = (_Float16)a; r.y = (_Float16)b; return r;
}
__device__ __forceinline__ half2_t u2h2(unsigned u) { return __builtin_bit_cast(half2_t, u); }
__device__ __forceinline__ float h2get(unsigned u, int idx) {
    half2_t h = u2h2(u);
    return idx ? (float)h.y : (float)h.x;
}
__device__ __forceinline__ int dot4i8(int a, int b, int c) {
#if __has_builtin(__builtin_amdgcn_sdot4)
    return __builtin_amdgcn_sdot4(a, b, c, false);
#else
    int d;
    asm("v_dot4_i32_i8 %0, %1, %2, %3" : "=v"(d) : "v"(a), "v"(b), "v"(c));
    return d;
#endif
}
// barrier draining only LDS (lgkm); global loads/stores stay in flight.
#define BAR_LDS() asm volatile("s_waitcnt lgkmcnt(0)\n\ts_barrier" ::: "memory")

// Grid 224 x 256, all co-resident (1 WG/CU).
//  bid <  32 : consumer — TWO batches (2*bid, 2*bid+1). One column per thread,
//              full k=256; int8 weights for all 3 gates in VGPRs (192 dw,
//              SHARED by both batches). The two independent recurrence chains
//              interleave in each wave -> ILP hides the latency that bounded
//              R11 (1 wave/SIMD, single chain, ~70% stall).
//  bid >= 32 : producer (gate g, batch b) — x-projections into ring in ws.
extern "C" __global__ void __launch_bounds__(NTHR)
gru_fused(const float* __restrict__ x,
          const float* __restrict__ Wz, const float* __restrict__ bz,
          const float* __restrict__ Wr, const float* __restrict__ br,
          const float* __restrict__ Wh, const float* __restrict__ bh,
          float* __restrict__ out,
          unsigned* prodflag, unsigned* consflag,
          unsigned long long* preZR, unsigned* preH, int ring)
{
    __shared__ __align__(16) unsigned smem[LDS_DW];
    const int tid = threadIdx.x;
    const int bid = blockIdx.x;
    const int rmask = ring - 1;

    if (bid >= NCONS) {
        // ---------------- producer ----------------
        const int pb = bid - NCONS;     // 0..191
        const int g  = pb >> 6;         // 0=z 1=r 2=h
        const int b  = pb & 63;
        const float* W    = (g == 0) ? Wz : (g == 1) ? Wr : Wh;
        const float* bias = (g == 0) ? bz : (g == 1) ? br : bh;
        const int kh = tid & 1;         // k-half (128 x-inputs)
        const int c2 = tid >> 1;        // col-pair 0..127
        const int c0 = c2 * 2, c1 = c0 + 1;

        half2_t wa[64], wb[64];         // x-part rows kh*128..+127, cols c0,c1
        #pragma unroll
        for (int j = 0; j < 64; ++j) {
            const int k = kh * 128 + 2 * j;
            wa[j] = mkh2(W[k * NH + c0], W[(k + 1) * NH + c0]);
            wb[j] = mkh2(W[k * NH + c1], W[(k + 1) * NH + c1]);
        }
        const float bv0 = bias[c0], bv1 = bias[c1];

        for (int ch = 0; ch < NCHUNK; ++ch) {
            const int lead = ch * CHUNK + CHUNK - ring;
            if (lead > 0) {
                if (tid == 0) {
                    unsigned it = 0;
                    while ((int)__hip_atomic_load(&consflag[b], __ATOMIC_RELAXED,
                                                  __HIP_MEMORY_SCOPE_AGENT) < lead) {
                        __builtin_amdgcn_s_sleep(8);
                        if (++it > (1u << 20)) break;
                    }
                }
                __syncthreads();
            }
            const int t0 = ch * CHUNK;
            {   // stage x[b][t0..t0+31][:] into LDS as half2, row stride 132 dw
                const float4* xs = reinterpret_cast<const float4*>(
                    x + (size_t)b * NT * ND + (size_t)t0 * ND);
                #pragma unroll
                for (int rep = 0; rep < 8; ++rep) {
                    const int f = rep * NTHR + tid;     // 0..2047 float4s
                    const float4 v = xs[f];
                    const int tt = f >> 6;
                    const int u2 = f & 63;
                    uint2 pk;
                    pk.x = __builtin_bit_cast(unsigned, mkh2(v.x, v.y));
                    pk.y = __builtin_bit_cast(unsigned, mkh2(v.z, v.w));
                    *reinterpret_cast<uint2*>(&smem[tt * XT_STRIDE + u2 * 2]) = pk;
                }
            }
            __syncthreads();
            #pragma unroll 1
            for (int t = 0; t < CHUNK; ++t) {
                const uint4* xr4 = reinterpret_cast<const uint4*>(
                    &smem[t * XT_STRIDE + kh * 64]);
                float a00 = 0.f, a01 = 0.f, a10 = 0.f, a11 = 0.f;
                #pragma unroll
                for (int i = 0; i < 16; ++i) {
                    const uint4 xv = xr4[i];
                    a00 = __builtin_amdgcn_fdot2(u2h2(xv.x), wa[i*4+0], a00, false);
                    a01 = __builtin_amdgcn_fdot2(u2h2(xv.y), wa[i*4+1], a01, false);
                    a00 = __builtin_amdgcn_fdot2(u2h2(xv.z), wa[i*4+2], a00, false);
                    a01 = __builtin_amdgcn_fdot2(u2h2(xv.w), wa[i*4+3], a01, false);
                    a10 = __builtin_amdgcn_fdot2(u2h2(xv.x), wb[i*4+0], a10, false);
                    a11 = __builtin_amdgcn_fdot2(u2h2(xv.y), wb[i*4+1], a11, false);
                    a10 = __builtin_amdgcn_fdot2(u2h2(xv.z), wb[i*4+2], a10, false);
                    a11 = __builtin_amdgcn_fdot2(u2h2(xv.w), wb[i*4+3], a11, false);
                }
                float a0 = a00 + a01, a1 = a10 + a11;
                a0 += __shfl_xor(a0, 1, 64);   // combine k-halves (lane pairs)
                a1 += __shfl_xor(a1, 1, 64);
                a0 += bv0; a1 += bv1;
                if (kh == 0) {
                    const unsigned pk = __builtin_bit_cast(unsigned, mkh2(a0, a1));
                    const size_t slot = (size_t)b * ring + ((t0 + t) & rmask);
                    if (g == 2) {
                        __hip_atomic_store(&preH[slot * 128 + c2], pk,
                                           __ATOMIC_RELAXED, __HIP_MEMORY_SCOPE_AGENT);
                    } else {
                        unsigned* zr32 = reinterpret_cast<unsigned*>(&preZR[slot * 128 + c2]);
                        __hip_atomic_store(&zr32[g], pk,
                                           __ATOMIC_RELAXED, __HIP_MEMORY_SCOPE_AGENT);
                    }
                }
            }
            asm volatile("s_waitcnt vmcnt(0)" ::: "memory");  // drain ring stores
            __syncthreads();
            if (tid == 0)
                __hip_atomic_store(&prodflag[b * 3 + g], (unsigned)(ch + 1),
                                   __ATOMIC_RELAXED, __HIP_MEMORY_SCOPE_AGENT);
            __syncthreads();
        }
        return;
    }

    // ------------- consumer: recurrence for batches b0, b1 -------------
    const int b0   = bid * 2;
    const int b1   = b0 + 1;
    const int c    = tid;          // column 0..255 (one per thread)
    const int lane = tid & 63;
    const int sub  = c & 1;        // half of the packed pre col-pair

    // per-thread per-gate max |w| over the full 256-k column -> quant scales
    float mxz = 1e-8f, mxr = 1e-8f, mxh = 1e-8f;
    #pragma unroll 4
    for (int j = 0; j < 256; ++j) {
        mxz = fmaxf(mxz, fabsf(Wz[(ND + j) * NH + c]));
        mxr = fmaxf(mxr, fabsf(Wr[(ND + j) * NH + c]));
        mxh = fmaxf(mxh, fabsf(Wh[(ND + j) * NH + c]));
    }
    const float qsz = 127.0f / mxz, qsr = 127.0f / mxr, qsh = 127.0f / mxh;
    const float deqz = mxz / (127.0f * 127.0f);
    const float deqr = mxr / (127.0f * 127.0f);
    const float deqh = mxh / (127.0f * 127.0f);

    // quantize + pack: 16 uint4 per gate = 192 VGPRs, SHARED by both batches
    uint4 wz4[16], wr4[16], wh4[16];
    #pragma unroll
    for (int i = 0; i < 16; ++i) {
        unsigned dz[4], dr[4], dh[4];
        #pragma unroll
        for (int d = 0; d < 4; ++d) {
            unsigned az = 0, ar = 0, ah = 0;
            #pragma unroll
            for (int j = 0; j < 4; ++j) {
                const int k = ND + (i * 4 + d) * 4 + j;
                const int qz = __float2int_rn(Wz[k * NH + c] * qsz);
                const int qr = __float2int_rn(Wr[k * NH + c] * qsr);
                const int qh = __float2int_rn(Wh[k * NH + c] * qsh);
                az |= ((unsigned)(qz & 255)) << (8 * j);
                ar |= ((unsigned)(qr & 255)) << (8 * j);
                ah |= ((unsigned)(qh & 255)) << (8 * j);
            }
            dz[d] = az; dr[d] = ar; dh[d] = ah;
        }
        wz4[i] = make_uint4(dz[0], dz[1], dz[2], dz[3]);
        wr4[i] = make_uint4(dr[0], dr[1], dr[2], dr[3]);
        wh4[i] = make_uint4(dh[0], dh[1], dh[2], dh[3]);
    }

    smem[tid] = 0u;   // zero hq0/vq0/hq1/vq1 (dw 0..255)
    float hreg0 = 0.f, hreg1 = 0.f;

    // wait for chunk 0 of all 3 gates, both batches
    if (tid < 6) {
        const int bb = (tid < 3) ? b0 : b1;
        const int g  = (tid < 3) ? tid : tid - 3;
        unsigned it = 0;
        while (__hip_atomic_load(&prodflag[bb * 3 + g], __ATOMIC_RELAXED,
                                 __HIP_MEMORY_SCOPE_AGENT) < 1u) {
            __builtin_amdgcn_s_sleep(8);
            if (++it > (1u << 20)) break;
        }
    }
    __syncthreads();

    const unsigned long long* zrb0 = preZR + (size_t)b0 * ring * 128 + (c >> 1);
    const unsigned*           hhb0 = preH  + (size_t)b0 * ring * 128 + (c >> 1);
    const unsigned long long* zrb1 = preZR + (size_t)b1 * ring * 128 + (c >> 1);
    const unsigned*           hhb1 = preH  + (size_t)b1 * ring * 128 + (c >> 1);
    float* outb0 = out + (size_t)b0 * NT * NH + c;
    float* outb1 = out + (size_t)b1 * NT * NH + c;
    const uint4* lds4 = reinterpret_cast<const uint4*>(smem);
    char* ldsb = reinterpret_cast<char*>(smem);

    unsigned long long zr0 = __hip_atomic_load(zrb0, __ATOMIC_RELAXED, __HIP_MEMORY_SCOPE_AGENT);
    unsigned           hh0 = __hip_atomic_load(hhb0, __ATOMIC_RELAXED, __HIP_MEMORY_SCOPE_AGENT);
    unsigned long long zr1 = __hip_atomic_load(zrb1, __ATOMIC_RELAXED, __HIP_MEMORY_SCOPE_AGENT);
    unsigned           hh1 = __hip_atomic_load(hhb1, __ATOMIC_RELAXED, __HIP_MEMORY_SCOPE_AGENT);

    #pragma unroll 1
    for (int t = 0; t < NT; ++t) {
        const int tn = t + 1;
        const bool pf = (tn < NT) && ((tn & (CHUNK - 1)) != 0);

        // ---- stage A: z, r dots for BOTH batches (interleaved chains) ----
        const uint4 hv0 = lds4[lane & 15];         // batch0 h (broadcast b128)
        const uint4 hv1 = lds4[32 + (lane & 15)];  // batch1 h
        int az00 = 0, az01 = 0, az02 = 0, az03 = 0;
        int ar00 = 0, ar01 = 0, ar02 = 0, ar03 = 0;
        int az10 = 0, az11 = 0, az12 = 0, az13 = 0;
        int ar10 = 0, ar11 = 0, ar12 = 0, ar13 = 0;
        #pragma unroll
        for (int i = 0; i < 16; ++i) {
            const int s0x = __builtin_amdgcn_readlane((int)hv0.x, i);
            const int s0y = __builtin_amdgcn_readlane((int)hv0.y, i);
            const int s0z = __builtin_amdgcn_readlane((int)hv0.z, i);
            const int s0w = __builtin_amdgcn_readlane((int)hv0.w, i);
            const int s1x = __builtin_amdgcn_readlane((int)hv1.x, i);
            const int s1y = __builtin_amdgcn_readlane((int)hv1.y, i);
            const int s1z = __builtin_amdgcn_readlane((int)hv1.z, i);
            const int s1w = __builtin_amdgcn_readlane((int)hv1.w, i);
            az00 = dot4i8(s0x, (int)wz4[i].x, az00);
            az10 = dot4i8(s1x, (int)wz4[i].x, az10);
            az01 = dot4i8(s0y, (int)wz4[i].y, az01);
            az11 = dot4i8(s1y, (int)wz4[i].y, az11);
            az02 = dot4i8(s0z, (int)wz4[i].z, az02);
            az12 = dot4i8(s1z, (int)wz4[i].z, az12);
            az03 = dot4i8(s0w, (int)wz4[i].w, az03);
            az13 = dot4i8(s1w, (int)wz4[i].w, az13);
            ar00 = dot4i8(s0x, (int)wr4[i].x, ar00);
            ar10 = dot4i8(s1x, (int)wr4[i].x, ar10);
            ar01 = dot4i8(s0y, (int)wr4[i].y, ar01);
            ar11 = dot4i8(s1y, (int)wr4[i].y, ar11);
            ar02 = dot4i8(s0z, (int)wr4[i].z, ar02);
            ar12 = dot4i8(s1z, (int)wr4[i].z, ar12);
            ar03 = dot4i8(s0w, (int)wr4[i].w, ar03);
            ar13 = dot4i8(s1w, (int)wr4[i].w, ar13);
        }
        const float azf0 = (float)((az00 + az01) + (az02 + az03)) * deqz;
        const float arf0 = (float)((ar00 + ar01) + (ar02 + ar03)) * deqr;
        const float azf1 = (float)((az10 + az11) + (az12 + az13)) * deqz;
        const float arf1 = (float)((ar10 + ar11) + (ar12 + ar13)) * deqr;
        const float z0 = sigmoid_f(azf0 + h2get((unsigned)(zr0 & 0xffffffffu), sub));
        const float r0 = sigmoid_f(arf0 + h2get((unsigned)(zr0 >> 32), sub));
        const float z1 = sigmoid_f(azf1 + h2get((unsigned)(zr1 & 0xffffffffu), sub));
        const float r1 = sigmoid_f(arf1 + h2get((unsigned)(zr1 >> 32), sub));
        const float v0 = r0 * hreg0;
        const float v1 = r1 * hreg1;
        ldsb[256 + c] = (char)__float2int_rn(v0 * 127.0f);
        ldsb[768 + c] = (char)__float2int_rn(v1 * 127.0f);

        // prefetch next step's pre-activations (lands under stage B)
        unsigned long long zrn0 = 0, zrn1 = 0; unsigned hhn0 = 0, hhn1 = 0;
        if (pf) {
            const int so = (tn & rmask) * 128;
            zrn0 = __hip_atomic_load(zrb0 + so, __ATOMIC_RELAXED, __HIP_MEMORY_SCOPE_AGENT);
            hhn0 = __hip_atomic_load(hhb0 + so, __ATOMIC_RELAXED, __HIP_MEMORY_SCOPE_AGENT);
            zrn1 = __hip_atomic_load(zrb1 + so, __ATOMIC_RELAXED, __HIP_MEMORY_SCOPE_AGENT);
            hhn1 = __hip_atomic_load(hhb1 + so, __ATOMIC_RELAXED, __HIP_MEMORY_SCOPE_AGENT);
        }
        BAR_LDS();   // vq0/vq1 ready

        // ---- stage B: h_hat dots for BOTH batches, then h_new ----
        const uint4 vv0 = lds4[16 + (lane & 15)];
        const uint4 vv1 = lds4[48 + (lane & 15)];
        int ah00 = 0, ah01 = 0, ah02 = 0, ah03 = 0;
        int ah10 = 0, ah11 = 0, ah12 = 0, ah13 = 0;
        #pragma unroll
        for (int i = 0; i < 16; ++i) {
            const int s0x = __builtin_amdgcn_readlane((int)vv0.x, i);
            const int s0y = __builtin_amdgcn_readlane((int)vv0.y, i);
            const int s0z = __builtin_amdgcn_readlane((int)vv0.z, i);
            const int s0w = __builtin_amdgcn_readlane((int)vv0.w, i);
            const int s1x = __builtin_amdgcn_readlane((int)vv1.x, i);
            const int s1y = __builtin_amdgcn_readlane((int)vv1.y, i);
            const int s1z = __builtin_amdgcn_readlane((int)vv1.z, i);
            const int s1w = __builtin_amdgcn_readlane((int)vv1.w, i);
            ah00 = dot4i8(s0x, (int)wh4[i].x, ah00);
            ah10 = dot4i8(s1x, (int)wh4[i].x, ah10);
            ah01 = dot4i8(s0y, (int)wh4[i].y, ah01);
            ah11 = dot4i8(s1y, (int)wh4[i].y, ah11);
            ah02 = dot4i8(s0z, (int)wh4[i].z, ah02);
            ah12 = dot4i8(s1z, (int)wh4[i].z, ah12);
            ah03 = dot4i8(s0w, (int)wh4[i].w, ah03);
            ah13 = dot4i8(s1w, (int)wh4[i].w, ah13);
        }
        const float ahf0 = (float)((ah00 + ah01) + (ah02 + ah03)) * deqh;
        const float ahf1 = (float)((ah10 + ah11) + (ah12 + ah13)) * deqh;
        const float hhat0 = tanh_f(ahf0 + h2get(hh0, sub));
        const float hhat1 = tanh_f(ahf1 + h2get(hh1, sub));
        const float hn0 = hreg0 + z0 * (hhat0 - hreg0);
        const float hn1 = hreg1 + z1 * (hhat1 - hreg1);
        hreg0 = hn0; hreg1 = hn1;
        outb0[(size_t)t * NH] = hn0;
        outb1[(size_t)t * NH] = hn1;
        ldsb[c]       = (char)__float2int_rn(hn0 * 127.0f);
        ldsb[512 + c] = (char)__float2int_rn(hn1 * 127.0f);
        BAR_LDS();   // hq0/hq1 = h_t everywhere

        if (pf) {
            zr0 = zrn0; hh0 = hhn0; zr1 = zrn1; hh1 = hhn1;
        } else if (tn < NT) {        // chunk boundary: publish + poll + reload
            if (tid == 0) {
                __hip_atomic_store(&consflag[b0], (unsigned)tn,
                                   __ATOMIC_RELAXED, __HIP_MEMORY_SCOPE_AGENT);
                __hip_atomic_store(&consflag[b1], (unsigned)tn,
                                   __ATOMIC_RELAXED, __HIP_MEMORY_SCOPE_AGENT);
            }
            const unsigned need = (unsigned)((tn >> 5) + 1);
            if (tid < 6) {
                const int bb = (tid < 3) ? b0 : b1;
                const int g  = (tid < 3) ? tid : tid - 3;
                unsigned it = 0;
                while (__hip_atomic_load(&prodflag[bb * 3 + g], __ATOMIC_RELAXED,
                                         __HIP_MEMORY_SCOPE_AGENT) < need) {
                    __builtin_amdgcn_s_sleep(8);
                    if (++it > (1u << 20)) break;
                }
            }
            __syncthreads();
            const int so = (tn & rmask) * 128;
            zr0 = __hip_atomic_load(zrb0 + so, __ATOMIC_RELAXED, __HIP_MEMORY_SCOPE_AGENT);
            hh0 = __hip_atomic_load(hhb0 + so, __ATOMIC_RELAXED, __HIP_MEMORY_SCOPE_AGENT);
            zr1 = __hip_atomic_load(zrb1 + so, __ATOMIC_RELAXED, __HIP_MEMORY_SCOPE_AGENT);
            hh1 = __hip_atomic_load(hhb1 + so, __ATOMIC_RELAXED, __HIP_MEMORY_SCOPE_AGENT);
        }
    }
}

extern "C" void kernel_launch(void* const* d_in, const int* in_sizes, int n_in,
                              void* d_out, int out_size, void* d_ws, size_t ws_size,
                              hipStream_t stream) {
    const float* x  = (const float*)d_in[0];
    const float* Wz = (const float*)d_in[1];
    const float* bz = (const float*)d_in[2];
    const float* Wr = (const float*)d_in[3];
    const float* br = (const float*)d_in[4];
    const float* Wh = (const float*)d_in[5];
    const float* bh = (const float*)d_in[6];
    float* outp = (float*)d_out;

    // ring sizing: per ring-step bytes = NB*128*12 = 96 KiB
    const size_t base = 4096;
    int ring = 32;
    for (int r = 2048; r >= 32; r >>= 1) {
        const size_t need = base + (size_t)NB * r * 128 * 12;
        if (need <= ws_size) { ring = r; break; }
    }
    char* w = (char*)d_ws;
    unsigned* prodflag = (unsigned*)w;                 // [64][3]
    unsigned* consflag = (unsigned*)(w + 1024);        // [64]
    unsigned long long* preZR = (unsigned long long*)(w + base);          // [64][ring][128]
    unsigned* preH = (unsigned*)(w + base + (size_t)NB * ring * 128 * 8); // [64][ring][128]

    hipMemsetAsync(w, 0, 4096, stream);  // flags must start at 0 each launch
    gru_fused<<<GRID, NTHR, 0, stream>>>(x, Wz, bz, Wr, br, Wh, bh, outp,
                                         prodflag, consflag, preZR, preH, ring);
}